// Round 1
// baseline (591.243 us; speedup 1.0000x reference)
//
#include <hip/hip_runtime.h>

#define HF 32
#define EPS 1e-5f

__device__ __forceinline__ float leaky(float v){ return fmaxf(v, 0.01f*v); }
__device__ __forceinline__ float elu1(float v){ return v > 0.f ? v : (expf(v)-1.f); }
__device__ __forceinline__ float sigmoidf(float v){ return 1.f/(1.f+expf(-v)); }

// ---------------- input MLP: h = leaky(leaky(x@W1+b1)@W2+b2) ----------------
__global__ __launch_bounds__(256)
void k_mlp(const float* __restrict__ x,
           const float* __restrict__ w1, const float* __restrict__ b1,
           const float* __restrict__ w2, const float* __restrict__ b2,
           float* __restrict__ h, int N){
    __shared__ float sW1[3*HF], sB1[HF], sW2[HF*HF], sB2[HF];
    int t = threadIdx.x;
    for (int i = t; i < 3*HF; i += 256) sW1[i] = w1[i];
    if (t < HF){ sB1[t] = b1[t]; sB2[t] = b2[t]; }
    for (int i = t; i < HF*HF; i += 256) sW2[i] = w2[i];
    __syncthreads();
    int n = blockIdx.x*256 + t;
    if (n >= N) return;
    float x0 = x[(size_t)n*3], x1 = x[(size_t)n*3+1], x2 = x[(size_t)n*3+2];
    float h1[HF];
#pragma unroll
    for (int j = 0; j < HF; j++){
        float v = fmaf(x0, sW1[j], fmaf(x1, sW1[HF+j], fmaf(x2, sW1[2*HF+j], sB1[j])));
        h1[j] = leaky(v);
    }
    float4* hv = (float4*)(h + (size_t)n*HF);
#pragma unroll
    for (int jb = 0; jb < 8; jb++){
        float o[4];
#pragma unroll
        for (int c = 0; c < 4; c++){
            int j = jb*4 + c;
            float v = sB2[j];
#pragma unroll
            for (int i = 0; i < HF; i++) v = fmaf(h1[i], sW2[i*HF+j], v);
            o[c] = leaky(v);
        }
        hv[jb] = make_float4(o[0], o[1], o[2], o[3]);
    }
}

// ---------------- batchnorm stats: stats[0..31]=sum, [32..63]=sumsq ----------
__global__ __launch_bounds__(256)
void k_stats(const float* __restrict__ h, float* __restrict__ stats, int N){
    int f = threadIdx.x & 31, j = threadIdx.x >> 5;   // 32 features x 8 lanes
    int base = blockIdx.x * 256;
    float s = 0.f, ss = 0.f;
    for (int i = 0; i < 32; i++){
        int n = base + j + i*8;
        if (n < N){ float v = h[(size_t)n*HF + f]; s += v; ss += v*v; }
    }
    __shared__ float ls[HF], lss[HF];
    if (threadIdx.x < HF){ ls[threadIdx.x] = 0.f; lss[threadIdx.x] = 0.f; }
    __syncthreads();
    atomicAdd(&ls[f], s); atomicAdd(&lss[f], ss);
    __syncthreads();
    if (threadIdx.x < HF) atomicAdd(&stats[threadIdx.x], ls[threadIdx.x]);
    else if (threadIdx.x < 2*HF) atomicAdd(&stats[threadIdx.x], lss[threadIdx.x - HF]);
}

// ---------------- degree count over dst ----------------
__global__ __launch_bounds__(256)
void k_count(const int* __restrict__ dst, int* __restrict__ cnt, int E){
    int e = blockIdx.x*256 + threadIdx.x;
    if (e < E) atomicAdd(&cnt[dst[e]], 1);
}

// ---------------- 3-kernel exclusive scan of cnt -> row_ptr; dis=rsqrt(cnt+1)
__global__ __launch_bounds__(256)
void k_scan1(const int* __restrict__ cnt, int* __restrict__ bsum, int N){
    __shared__ int l[256];
    int i = blockIdx.x*256 + threadIdx.x;
    l[threadIdx.x] = (i < N) ? cnt[i] : 0;
    __syncthreads();
    for (int off = 128; off > 0; off >>= 1){
        if (threadIdx.x < off) l[threadIdx.x] += l[threadIdx.x + off];
        __syncthreads();
    }
    if (threadIdx.x == 0) bsum[blockIdx.x] = l[0];
}

__global__ __launch_bounds__(512)
void k_scan2(const int* __restrict__ bsum, int* __restrict__ boff, int NB){
    // NB must be <= 512 (N=100000 -> NB=391)
    __shared__ int l[512];
    int t = threadIdx.x;
    int v = (t < NB) ? bsum[t] : 0;
    l[t] = v; __syncthreads();
    for (int off = 1; off < 512; off <<= 1){
        int u = (t >= off) ? l[t - off] : 0;
        __syncthreads();
        l[t] += u;
        __syncthreads();
    }
    if (t < NB) boff[t] = l[t] - v;
}

__global__ __launch_bounds__(256)
void k_scan3(const int* __restrict__ cnt, const int* __restrict__ boff,
             int* __restrict__ rowp, float* __restrict__ dis, int N, int E){
    __shared__ int l[256];
    int t = threadIdx.x; int i = blockIdx.x*256 + t;
    int v = (i < N) ? cnt[i] : 0;
    l[t] = v; __syncthreads();
    for (int off = 1; off < 256; off <<= 1){
        int u = (t >= off) ? l[t - off] : 0;
        __syncthreads();
        l[t] += u;
        __syncthreads();
    }
    if (i < N){
        rowp[i] = boff[blockIdx.x] + l[t] - v;
        dis[i]  = rsqrtf((float)(v + 1));
    }
    if (i == 0) rowp[N] = E;
}

// ---------------- place edges into CSR ----------------
__global__ __launch_bounds__(256)
void k_place(const int* __restrict__ src, const int* __restrict__ dst,
             const int* __restrict__ rowp, int* __restrict__ fill,
             int* __restrict__ esrc, int E){
    int e = blockIdx.x*256 + threadIdx.x;
    if (e < E){
        int d = dst[e];
        int pos = rowp[d] + atomicAdd(&fill[d], 1);
        esrc[pos] = src[e];
    }
}

// ---------------- BN + first transform: t1 = ((bn(h))@W)*dis ----------------
__global__ __launch_bounds__(256)
void k_bn_t1(const float* __restrict__ h, const float* __restrict__ stats,
             const float* __restrict__ gamma, const float* __restrict__ beta,
             const float* __restrict__ W, const float* __restrict__ dis,
             float* __restrict__ tout, int N){
    __shared__ float sW[HF*HF];
    __shared__ float sh[32][36];
    int tid = threadIdx.x;
    for (int i = tid; i < HF*HF; i += 256) sW[i] = W[i];
    int nib = tid >> 3, l = tid & 7;
    int n = blockIdx.x*32 + nib;
    float4 hv = make_float4(0.f,0.f,0.f,0.f);
    float d = 0.f;
    if (n < N){
        hv = ((const float4*)h)[(size_t)n*8 + l];
        d = dis[n];
        float inv = 1.0f / (float)N;
        float* hp = (float*)&hv;
#pragma unroll
        for (int c = 0; c < 4; c++){
            int f = 4*l + c;
            float mu  = stats[f]    * inv;
            float var = stats[HF+f] * inv - mu*mu;
            float rs  = rsqrtf(var + EPS);
            hp[c] = (hp[c] - mu) * rs * gamma[f] + beta[f];
        }
    }
    __syncthreads();                // covers sW writes
    *(float4*)&sh[nib][4*l] = hv;
    __syncthreads();
    float4 o = make_float4(0.f,0.f,0.f,0.f);
#pragma unroll
    for (int i = 0; i < HF; i++){
        float hvv = sh[nib][i];
        float4 w = *(const float4*)&sW[i*HF + 4*l];
        o.x = fmaf(hvv, w.x, o.x); o.y = fmaf(hvv, w.y, o.y);
        o.z = fmaf(hvv, w.z, o.z); o.w = fmaf(hvv, w.w, o.w);
    }
    if (n < N){
        o.x *= d; o.y *= d; o.z *= d; o.w *= d;
        ((float4*)tout)[(size_t)n*8 + l] = o;
    }
}

// ------- fused gather + next transform: h=elu(dis*(self+sum)+b); t=(h@W)*dis
__global__ __launch_bounds__(256)
void k_gather_t(const float4* __restrict__ tin, const int* __restrict__ esrc,
                const int* __restrict__ rowp, const float* __restrict__ dis,
                const float* __restrict__ bias, const float* __restrict__ W,
                float4* __restrict__ tout, int N){
    __shared__ float sW[HF*HF];
    __shared__ float sh[32][36];
    int tid = threadIdx.x;
    for (int i = tid; i < HF*HF; i += 256) sW[i] = W[i];
    int nib = tid >> 3, l = tid & 7;
    int n = blockIdx.x*32 + nib;
    float4 acc = make_float4(0.f,0.f,0.f,0.f);
    float d = 0.f;
    if (n < N){
        acc = tin[(size_t)n*8 + l];          // self loop term
        int e0 = rowp[n], e1 = rowp[n+1];
        for (int e = e0; e < e1; e++){
            int s = esrc[e];
            float4 v = tin[(size_t)s*8 + l];
            acc.x += v.x; acc.y += v.y; acc.z += v.z; acc.w += v.w;
        }
        d = dis[n];
        float4 b4 = *(const float4*)&bias[4*l];
        acc.x = elu1(fmaf(d, acc.x, b4.x));
        acc.y = elu1(fmaf(d, acc.y, b4.y));
        acc.z = elu1(fmaf(d, acc.z, b4.z));
        acc.w = elu1(fmaf(d, acc.w, b4.w));
    }
    __syncthreads();                // covers sW writes
    *(float4*)&sh[nib][4*l] = acc;
    __syncthreads();
    float4 o = make_float4(0.f,0.f,0.f,0.f);
#pragma unroll
    for (int i = 0; i < HF; i++){
        float hvv = sh[nib][i];
        float4 w = *(const float4*)&sW[i*HF + 4*l];
        o.x = fmaf(hvv, w.x, o.x); o.y = fmaf(hvv, w.y, o.y);
        o.z = fmaf(hvv, w.z, o.z); o.w = fmaf(hvv, w.w, o.w);
    }
    if (n < N){
        o.x *= d; o.y *= d; o.z *= d; o.w *= d;
        tout[(size_t)n*8 + l] = o;
    }
}

// ------- final: gather layer3 + elu, then output MLP + sigmoid on col 0 -----
__global__ __launch_bounds__(256)
void k_gather_out(const float4* __restrict__ tin, const int* __restrict__ esrc,
                  const int* __restrict__ rowp, const float* __restrict__ dis,
                  const float* __restrict__ bg3,
                  const float* __restrict__ wo1, const float* __restrict__ bo1,
                  const float* __restrict__ wo2, const float* __restrict__ bo2,
                  const float* __restrict__ wo3, const float* __restrict__ bo3,
                  float* __restrict__ out, int N){
    __shared__ float sW1[HF*HF], sW2[HF*HF], sW3[HF*4];
    __shared__ float sh[32][36], sh2[32][36];
    int tid = threadIdx.x;
    for (int i = tid; i < HF*HF; i += 256){ sW1[i] = wo1[i]; sW2[i] = wo2[i]; }
    if (tid < HF*4) sW3[tid] = wo3[tid];
    int nib = tid >> 3, l = tid & 7;
    int n = blockIdx.x*32 + nib;
    float4 acc = make_float4(0.f,0.f,0.f,0.f);
    if (n < N){
        acc = tin[(size_t)n*8 + l];
        int e0 = rowp[n], e1 = rowp[n+1];
        for (int e = e0; e < e1; e++){
            int s = esrc[e];
            float4 v = tin[(size_t)s*8 + l];
            acc.x += v.x; acc.y += v.y; acc.z += v.z; acc.w += v.w;
        }
        float d = dis[n];
        float4 b4 = *(const float4*)&bg3[4*l];
        acc.x = elu1(fmaf(d, acc.x, b4.x));
        acc.y = elu1(fmaf(d, acc.y, b4.y));
        acc.z = elu1(fmaf(d, acc.z, b4.z));
        acc.w = elu1(fmaf(d, acc.w, b4.w));
    }
    __syncthreads();                // covers weight loads
    *(float4*)&sh[nib][4*l] = acc;
    __syncthreads();
    // r1 = leaky(h@wo1 + bo1)
    float4 o1 = *(const float4*)&bo1[4*l];
#pragma unroll
    for (int i = 0; i < HF; i++){
        float hvv = sh[nib][i];
        float4 w = *(const float4*)&sW1[i*HF + 4*l];
        o1.x = fmaf(hvv, w.x, o1.x); o1.y = fmaf(hvv, w.y, o1.y);
        o1.z = fmaf(hvv, w.z, o1.z); o1.w = fmaf(hvv, w.w, o1.w);
    }
    o1.x = leaky(o1.x); o1.y = leaky(o1.y); o1.z = leaky(o1.z); o1.w = leaky(o1.w);
    *(float4*)&sh2[nib][4*l] = o1;
    __syncthreads();
    // r2 = leaky(r1@wo2 + bo2) -> overwrite sh (all r1 reads done)
    float4 o2 = *(const float4*)&bo2[4*l];
#pragma unroll
    for (int i = 0; i < HF; i++){
        float hvv = sh2[nib][i];
        float4 w = *(const float4*)&sW2[i*HF + 4*l];
        o2.x = fmaf(hvv, w.x, o2.x); o2.y = fmaf(hvv, w.y, o2.y);
        o2.z = fmaf(hvv, w.z, o2.z); o2.w = fmaf(hvv, w.w, o2.w);
    }
    o2.x = leaky(o2.x); o2.y = leaky(o2.y); o2.z = leaky(o2.z); o2.w = leaky(o2.w);
    *(float4*)&sh[nib][4*l] = o2;
    __syncthreads();
    // out = r2@wo3 + bo3 ; sigmoid col 0
    if (n < N && l < 4){
        float v = bo3[l];
#pragma unroll
        for (int i = 0; i < HF; i++) v = fmaf(sh[nib][i], sW3[i*4 + l], v);
        if (l == 0) v = sigmoidf(v);
        out[(size_t)n*4 + l] = v;
    }
}

extern "C" void kernel_launch(void* const* d_in, const int* in_sizes, int n_in,
                              void* d_out, int out_size, void* d_ws, size_t ws_size,
                              hipStream_t stream) {
    const float* x     = (const float*)d_in[0];
    const float* w_in1 = (const float*)d_in[1];
    const float* b_in1 = (const float*)d_in[2];
    const float* w_in2 = (const float*)d_in[3];
    const float* b_in2 = (const float*)d_in[4];
    const float* gamma = (const float*)d_in[5];
    const float* beta  = (const float*)d_in[6];
    const float* wg1   = (const float*)d_in[7];
    const float* bg1   = (const float*)d_in[8];
    const float* wg2   = (const float*)d_in[9];
    const float* bg2   = (const float*)d_in[10];
    const float* wg3   = (const float*)d_in[11];
    const float* bg3   = (const float*)d_in[12];
    const float* wo1   = (const float*)d_in[13];
    const float* bo1   = (const float*)d_in[14];
    const float* wo2   = (const float*)d_in[15];
    const float* bo2   = (const float*)d_in[16];
    const float* wo3   = (const float*)d_in[17];
    const float* bo3   = (const float*)d_in[18];
    const int*   ei    = (const int*)d_in[19];

    int N = in_sizes[0] / 3;
    int E = in_sizes[19] / 2;

    char* w = (char*)d_ws;
    size_t o = 0;
    auto alloc = [&](size_t bytes){ size_t r = o; o = (o + bytes + 255) & ~(size_t)255; return r; };
    float* stats = (float*)(w + alloc(2*HF*sizeof(float)));
    int*   cnt   = (int*)  (w + alloc((size_t)N*4));
    int*   fill  = (int*)  (w + alloc((size_t)N*4));
    size_t zero_bytes = o;                       // zero stats+cnt+fill
    int NB1 = (N + 255) / 256;
    int*   bsum  = (int*)  (w + alloc((size_t)NB1*4));
    int*   boff  = (int*)  (w + alloc((size_t)NB1*4));
    int*   rowp  = (int*)  (w + alloc(((size_t)N+1)*4));
    float* dis   = (float*)(w + alloc((size_t)N*4));
    int*   esrc  = (int*)  (w + alloc((size_t)E*4));
    float* bufA  = (float*)(w + alloc((size_t)N*HF*4));
    float* bufB  = (float*)(w + alloc((size_t)N*HF*4));

    hipMemsetAsync(d_ws, 0, zero_bytes, stream);

    const int* src = ei;
    const int* dst = ei + E;
    int EB = (E + 255) / 256;
    int GB = (N + 31) / 32;

    k_mlp  <<<NB1, 256, 0, stream>>>(x, w_in1, b_in1, w_in2, b_in2, bufA, N);
    k_stats<<<NB1, 256, 0, stream>>>(bufA, stats, N);
    k_count<<<EB,  256, 0, stream>>>(dst, cnt, E);
    k_scan1<<<NB1, 256, 0, stream>>>(cnt, bsum, N);
    k_scan2<<<1,   512, 0, stream>>>(bsum, boff, NB1);
    k_scan3<<<NB1, 256, 0, stream>>>(cnt, boff, rowp, dis, N, E);
    k_place<<<EB,  256, 0, stream>>>(src, dst, rowp, fill, esrc, E);

    k_bn_t1   <<<GB, 256, 0, stream>>>(bufA, stats, gamma, beta, wg1, dis, bufB, N);
    k_gather_t<<<GB, 256, 0, stream>>>((const float4*)bufB, esrc, rowp, dis, bg1, wg2, (float4*)bufA, N);
    k_gather_t<<<GB, 256, 0, stream>>>((const float4*)bufA, esrc, rowp, dis, bg2, wg3, (float4*)bufB, N);
    k_gather_out<<<GB, 256, 0, stream>>>((const float4*)bufB, esrc, rowp, dis, bg3,
                                         wo1, bo1, wo2, bo2, wo3, bo3, (float*)d_out, N);
}

// Round 2
// 370.469 us; speedup vs baseline: 1.5959x; 1.5959x over previous
//
#include <hip/hip_runtime.h>

#define HF 32
#define EPS 1e-5f
#define BSH 8
#define BSZ 256          // nodes per bucket

__device__ __forceinline__ float leaky(float v){ return fmaxf(v, 0.01f*v); }
__device__ __forceinline__ float elu1(float v){ return v > 0.f ? v : (expf(v)-1.f); }
__device__ __forceinline__ float sigmoidf(float v){ return 1.f/(1.f+expf(-v)); }

// ---------------- input MLP: h = leaky(leaky(x@W1+b1)@W2+b2) ----------------
__global__ __launch_bounds__(256)
void k_mlp(const float* __restrict__ x,
           const float* __restrict__ w1, const float* __restrict__ b1,
           const float* __restrict__ w2, const float* __restrict__ b2,
           float* __restrict__ h, int N){
    __shared__ float sW1[3*HF], sB1[HF], sW2[HF*HF], sB2[HF];
    int t = threadIdx.x;
    for (int i = t; i < 3*HF; i += 256) sW1[i] = w1[i];
    if (t < HF){ sB1[t] = b1[t]; sB2[t] = b2[t]; }
    for (int i = t; i < HF*HF; i += 256) sW2[i] = w2[i];
    __syncthreads();
    int n = blockIdx.x*256 + t;
    if (n >= N) return;
    float x0 = x[(size_t)n*3], x1 = x[(size_t)n*3+1], x2 = x[(size_t)n*3+2];
    float h1[HF];
#pragma unroll
    for (int j = 0; j < HF; j++){
        float v = fmaf(x0, sW1[j], fmaf(x1, sW1[HF+j], fmaf(x2, sW1[2*HF+j], sB1[j])));
        h1[j] = leaky(v);
    }
    float4* hv = (float4*)(h + (size_t)n*HF);
#pragma unroll
    for (int jb = 0; jb < 8; jb++){
        float o[4];
#pragma unroll
        for (int c = 0; c < 4; c++){
            int j = jb*4 + c;
            float v = sB2[j];
#pragma unroll
            for (int i = 0; i < HF; i++) v = fmaf(h1[i], sW2[i*HF+j], v);
            o[c] = leaky(v);
        }
        hv[jb] = make_float4(o[0], o[1], o[2], o[3]);
    }
}

// ---------------- batchnorm stats: stats[0..31]=sum, [32..63]=sumsq ----------
__global__ __launch_bounds__(256)
void k_stats(const float* __restrict__ h, float* __restrict__ stats, int N){
    int f = threadIdx.x & 31, j = threadIdx.x >> 5;
    int base = blockIdx.x * 256;
    float s = 0.f, ss = 0.f;
    for (int i = 0; i < 32; i++){
        int n = base + j + i*8;
        if (n < N){ float v = h[(size_t)n*HF + f]; s += v; ss += v*v; }
    }
    __shared__ float ls[HF], lss[HF];
    if (threadIdx.x < HF){ ls[threadIdx.x] = 0.f; lss[threadIdx.x] = 0.f; }
    __syncthreads();
    atomicAdd(&ls[f], s); atomicAdd(&lss[f], ss);
    __syncthreads();
    if (threadIdx.x < HF) atomicAdd(&stats[threadIdx.x], ls[threadIdx.x]);
    else if (threadIdx.x < 2*HF) atomicAdd(&stats[threadIdx.x], lss[threadIdx.x - HF]);
}

// ------------- binning pass A: per-bucket edge counts (LDS-staged) ----------
__global__ __launch_bounds__(256)
void k_binA(const int* __restrict__ dst, int* __restrict__ gcnt, int E, int B){
    __shared__ int l[512];
    int t = threadIdx.x;
    for (int i = t; i < B; i += 256) l[i] = 0;
    __syncthreads();
    int base = blockIdx.x * 8192;
    for (int i = 0; i < 32; i++){
        int e = base + t + i*256;
        if (e < E) atomicAdd(&l[dst[e] >> BSH], 1);
    }
    __syncthreads();
    for (int i = t; i < B; i += 256){ int c = l[i]; if (c) atomicAdd(&gcnt[i], c); }
}

// ------------- scan bucket counts -> bucket offsets (B <= 512) --------------
__global__ __launch_bounds__(512)
void k_scanB(const int* __restrict__ gcnt, int* __restrict__ boff, int NB){
    __shared__ int l[512];
    int t = threadIdx.x;
    int v = (t < NB) ? gcnt[t] : 0;
    l[t] = v; __syncthreads();
    for (int off = 1; off < 512; off <<= 1){
        int u = (t >= off) ? l[t - off] : 0;
        __syncthreads();
        l[t] += u;
        __syncthreads();
    }
    if (t < NB) boff[t] = l[t] - v;
    if (t == NB-1) boff[NB] = l[t];
}

// ------------- binning pass C: scatter packed edges into bucket segments ----
__global__ __launch_bounds__(256)
void k_binC(const int* __restrict__ src, const int* __restrict__ dst,
            const int* __restrict__ boff, int* __restrict__ gfill,
            int* __restrict__ ep, int E, int B){
    __shared__ int lcnt[512], lbase[512], lpos[512];
    int t = threadIdx.x;
    for (int i = t; i < B; i += 256){ lcnt[i] = 0; lpos[i] = 0; }
    __syncthreads();
    int base = blockIdx.x * 8192;
    for (int i = 0; i < 32; i++){
        int e = base + t + i*256;
        if (e < E) atomicAdd(&lcnt[dst[e] >> BSH], 1);
    }
    __syncthreads();
    for (int i = t; i < B; i += 256){
        int c = lcnt[i];
        lbase[i] = c ? (boff[i] + atomicAdd(&gfill[i], c)) : 0;
    }
    __syncthreads();
    for (int i = 0; i < 32; i++){
        int e = base + t + i*256;
        if (e < E){
            int d = dst[e], b = d >> BSH;
            int p = lbase[b] + atomicAdd(&lpos[b], 1);
            ep[p] = (src[e] << BSH) | (d & (BSZ-1));
        }
    }
}

// ------------- per-bucket CSR build: rowp, dis, esrc ------------------------
__global__ __launch_bounds__(256)
void k_bucketD(const int* __restrict__ ep, const int* __restrict__ boff,
               int* __restrict__ rowp, float* __restrict__ dis,
               int* __restrict__ esrc, int N, int E, int B){
    __shared__ int lcnt[256], lpre[256], lfill[256], sc[256];
    int b = blockIdx.x, t = threadIdx.x;
    int e0 = boff[b], e1 = boff[b+1];
    lcnt[t] = 0; lfill[t] = 0;
    __syncthreads();
    for (int e = e0 + t; e < e1; e += 256) atomicAdd(&lcnt[ep[e] & (BSZ-1)], 1);
    __syncthreads();
    int v = lcnt[t];
    sc[t] = v; __syncthreads();
    for (int off = 1; off < 256; off <<= 1){
        int u = (t >= off) ? sc[t - off] : 0;
        __syncthreads();
        sc[t] += u;
        __syncthreads();
    }
    int pre = sc[t] - v;          // exclusive prefix within bucket
    lpre[t] = pre;
    int n = b*BSZ + t;
    if (n < N){
        rowp[n] = e0 + pre;
        dis[n]  = rsqrtf((float)(v + 1));
    }
    if (n == N) rowp[N] = E;
    if (b == B-1 && t == 0 && (N & (BSZ-1)) == 0) rowp[N] = E;
    __syncthreads();
    for (int e = e0 + t; e < e1; e += 256){
        int val = ep[e];
        int d = val & (BSZ-1);
        int p = lpre[d] + atomicAdd(&lfill[d], 1);
        esrc[e0 + p] = val >> BSH;
    }
}

// ---------------- BN + first transform: t1 = ((bn(h))@W)*dis ----------------
__global__ __launch_bounds__(256)
void k_bn_t1(const float* __restrict__ h, const float* __restrict__ stats,
             const float* __restrict__ gamma, const float* __restrict__ beta,
             const float* __restrict__ W, const float* __restrict__ dis,
             float* __restrict__ tout, int N){
    __shared__ float sW[HF*HF];
    __shared__ float sh[32][36];
    int tid = threadIdx.x;
    for (int i = tid; i < HF*HF; i += 256) sW[i] = W[i];
    int nib = tid >> 3, l = tid & 7;
    int n = blockIdx.x*32 + nib;
    float4 hv = make_float4(0.f,0.f,0.f,0.f);
    float d = 0.f;
    if (n < N){
        hv = ((const float4*)h)[(size_t)n*8 + l];
        d = dis[n];
        float inv = 1.0f / (float)N;
        float* hp = (float*)&hv;
#pragma unroll
        for (int c = 0; c < 4; c++){
            int f = 4*l + c;
            float mu  = stats[f]    * inv;
            float var = stats[HF+f] * inv - mu*mu;
            float rs  = rsqrtf(var + EPS);
            hp[c] = (hp[c] - mu) * rs * gamma[f] + beta[f];
        }
    }
    __syncthreads();
    *(float4*)&sh[nib][4*l] = hv;
    __syncthreads();
    float4 o = make_float4(0.f,0.f,0.f,0.f);
#pragma unroll
    for (int i = 0; i < HF; i++){
        float hvv = sh[nib][i];
        float4 w = *(const float4*)&sW[i*HF + 4*l];
        o.x = fmaf(hvv, w.x, o.x); o.y = fmaf(hvv, w.y, o.y);
        o.z = fmaf(hvv, w.z, o.z); o.w = fmaf(hvv, w.w, o.w);
    }
    if (n < N){
        o.x *= d; o.y *= d; o.z *= d; o.w *= d;
        ((float4*)tout)[(size_t)n*8 + l] = o;
    }
}

// ------- fused gather + next transform: h=elu(dis*(self+sum)+b); t=(h@W)*dis
__global__ __launch_bounds__(256)
void k_gather_t(const float4* __restrict__ tin, const int* __restrict__ esrc,
                const int* __restrict__ rowp, const float* __restrict__ dis,
                const float* __restrict__ bias, const float* __restrict__ W,
                float4* __restrict__ tout, int N){
    __shared__ float sW[HF*HF];
    __shared__ float sh[32][36];
    int tid = threadIdx.x;
    for (int i = tid; i < HF*HF; i += 256) sW[i] = W[i];
    int nib = tid >> 3, l = tid & 7;
    int n = blockIdx.x*32 + nib;
    float4 acc = make_float4(0.f,0.f,0.f,0.f);
    float d = 0.f;
    if (n < N){
        acc = tin[(size_t)n*8 + l];          // self loop term
        int e0 = rowp[n], e1 = rowp[n+1];
        int e = e0;
        for (; e + 3 < e1; e += 4){
            int s0 = esrc[e], s1 = esrc[e+1], s2 = esrc[e+2], s3 = esrc[e+3];
            float4 v0 = tin[(size_t)s0*8 + l];
            float4 v1 = tin[(size_t)s1*8 + l];
            float4 v2 = tin[(size_t)s2*8 + l];
            float4 v3 = tin[(size_t)s3*8 + l];
            acc.x += (v0.x+v1.x) + (v2.x+v3.x);
            acc.y += (v0.y+v1.y) + (v2.y+v3.y);
            acc.z += (v0.z+v1.z) + (v2.z+v3.z);
            acc.w += (v0.w+v1.w) + (v2.w+v3.w);
        }
        for (; e < e1; e++){
            int s = esrc[e];
            float4 v = tin[(size_t)s*8 + l];
            acc.x += v.x; acc.y += v.y; acc.z += v.z; acc.w += v.w;
        }
        d = dis[n];
        float4 b4 = *(const float4*)&bias[4*l];
        acc.x = elu1(fmaf(d, acc.x, b4.x));
        acc.y = elu1(fmaf(d, acc.y, b4.y));
        acc.z = elu1(fmaf(d, acc.z, b4.z));
        acc.w = elu1(fmaf(d, acc.w, b4.w));
    }
    __syncthreads();
    *(float4*)&sh[nib][4*l] = acc;
    __syncthreads();
    float4 o = make_float4(0.f,0.f,0.f,0.f);
#pragma unroll
    for (int i = 0; i < HF; i++){
        float hvv = sh[nib][i];
        float4 w = *(const float4*)&sW[i*HF + 4*l];
        o.x = fmaf(hvv, w.x, o.x); o.y = fmaf(hvv, w.y, o.y);
        o.z = fmaf(hvv, w.z, o.z); o.w = fmaf(hvv, w.w, o.w);
    }
    if (n < N){
        o.x *= d; o.y *= d; o.z *= d; o.w *= d;
        tout[(size_t)n*8 + l] = o;
    }
}

// ------- final: gather layer3 + elu, then output MLP + sigmoid on col 0 -----
__global__ __launch_bounds__(256)
void k_gather_out(const float4* __restrict__ tin, const int* __restrict__ esrc,
                  const int* __restrict__ rowp, const float* __restrict__ dis,
                  const float* __restrict__ bg3,
                  const float* __restrict__ wo1, const float* __restrict__ bo1,
                  const float* __restrict__ wo2, const float* __restrict__ bo2,
                  const float* __restrict__ wo3, const float* __restrict__ bo3,
                  float* __restrict__ out, int N){
    __shared__ float sW1[HF*HF], sW2[HF*HF], sW3[HF*4];
    __shared__ float sh[32][36], sh2[32][36];
    int tid = threadIdx.x;
    for (int i = tid; i < HF*HF; i += 256){ sW1[i] = wo1[i]; sW2[i] = wo2[i]; }
    if (tid < HF*4) sW3[tid] = wo3[tid];
    int nib = tid >> 3, l = tid & 7;
    int n = blockIdx.x*32 + nib;
    float4 acc = make_float4(0.f,0.f,0.f,0.f);
    if (n < N){
        acc = tin[(size_t)n*8 + l];
        int e0 = rowp[n], e1 = rowp[n+1];
        int e = e0;
        for (; e + 3 < e1; e += 4){
            int s0 = esrc[e], s1 = esrc[e+1], s2 = esrc[e+2], s3 = esrc[e+3];
            float4 v0 = tin[(size_t)s0*8 + l];
            float4 v1 = tin[(size_t)s1*8 + l];
            float4 v2 = tin[(size_t)s2*8 + l];
            float4 v3 = tin[(size_t)s3*8 + l];
            acc.x += (v0.x+v1.x) + (v2.x+v3.x);
            acc.y += (v0.y+v1.y) + (v2.y+v3.y);
            acc.z += (v0.z+v1.z) + (v2.z+v3.z);
            acc.w += (v0.w+v1.w) + (v2.w+v3.w);
        }
        for (; e < e1; e++){
            int s = esrc[e];
            float4 v = tin[(size_t)s*8 + l];
            acc.x += v.x; acc.y += v.y; acc.z += v.z; acc.w += v.w;
        }
        float d = dis[n];
        float4 b4 = *(const float4*)&bg3[4*l];
        acc.x = elu1(fmaf(d, acc.x, b4.x));
        acc.y = elu1(fmaf(d, acc.y, b4.y));
        acc.z = elu1(fmaf(d, acc.z, b4.z));
        acc.w = elu1(fmaf(d, acc.w, b4.w));
    }
    __syncthreads();
    *(float4*)&sh[nib][4*l] = acc;
    __syncthreads();
    float4 o1 = *(const float4*)&bo1[4*l];
#pragma unroll
    for (int i = 0; i < HF; i++){
        float hvv = sh[nib][i];
        float4 w = *(const float4*)&sW1[i*HF + 4*l];
        o1.x = fmaf(hvv, w.x, o1.x); o1.y = fmaf(hvv, w.y, o1.y);
        o1.z = fmaf(hvv, w.z, o1.z); o1.w = fmaf(hvv, w.w, o1.w);
    }
    o1.x = leaky(o1.x); o1.y = leaky(o1.y); o1.z = leaky(o1.z); o1.w = leaky(o1.w);
    *(float4*)&sh2[nib][4*l] = o1;
    __syncthreads();
    float4 o2 = *(const float4*)&bo2[4*l];
#pragma unroll
    for (int i = 0; i < HF; i++){
        float hvv = sh2[nib][i];
        float4 w = *(const float4*)&sW2[i*HF + 4*l];
        o2.x = fmaf(hvv, w.x, o2.x); o2.y = fmaf(hvv, w.y, o2.y);
        o2.z = fmaf(hvv, w.z, o2.z); o2.w = fmaf(hvv, w.w, o2.w);
    }
    o2.x = leaky(o2.x); o2.y = leaky(o2.y); o2.z = leaky(o2.z); o2.w = leaky(o2.w);
    *(float4*)&sh[nib][4*l] = o2;
    __syncthreads();
    if (n < N && l < 4){
        float v = bo3[l];
#pragma unroll
        for (int i = 0; i < HF; i++) v = fmaf(sh[nib][i], sW3[i*4 + l], v);
        if (l == 0) v = sigmoidf(v);
        out[(size_t)n*4 + l] = v;
    }
}

extern "C" void kernel_launch(void* const* d_in, const int* in_sizes, int n_in,
                              void* d_out, int out_size, void* d_ws, size_t ws_size,
                              hipStream_t stream) {
    const float* x     = (const float*)d_in[0];
    const float* w_in1 = (const float*)d_in[1];
    const float* b_in1 = (const float*)d_in[2];
    const float* w_in2 = (const float*)d_in[3];
    const float* b_in2 = (const float*)d_in[4];
    const float* gamma = (const float*)d_in[5];
    const float* beta  = (const float*)d_in[6];
    const float* wg1   = (const float*)d_in[7];
    const float* bg1   = (const float*)d_in[8];
    const float* wg2   = (const float*)d_in[9];
    const float* bg2   = (const float*)d_in[10];
    const float* wg3   = (const float*)d_in[11];
    const float* bg3   = (const float*)d_in[12];
    const float* wo1   = (const float*)d_in[13];
    const float* bo1   = (const float*)d_in[14];
    const float* wo2   = (const float*)d_in[15];
    const float* bo2   = (const float*)d_in[16];
    const float* wo3   = (const float*)d_in[17];
    const float* bo3   = (const float*)d_in[18];
    const int*   ei    = (const int*)d_in[19];

    int N = in_sizes[0] / 3;
    int E = in_sizes[19] / 2;
    int B = (N + BSZ - 1) >> BSH;          // buckets (<=512 required)

    char* w = (char*)d_ws;
    size_t o = 0;
    auto alloc = [&](size_t bytes){ size_t r = o; o = (o + bytes + 255) & ~(size_t)255; return r; };
    // ---- zeroed region ----
    float* stats = (float*)(w + alloc(2*HF*sizeof(float)));
    int*   gcnt  = (int*)  (w + alloc((size_t)B*4));
    int*   gfill = (int*)  (w + alloc((size_t)B*4));
    size_t zero_bytes = o;
    // ---- rest ----
    int*   boff  = (int*)  (w + alloc(((size_t)B+1)*4));
    int*   ep    = (int*)  (w + alloc((size_t)E*4));
    int*   esrc  = (int*)  (w + alloc((size_t)E*4));
    int*   rowp  = (int*)  (w + alloc(((size_t)N+1)*4));
    float* dis   = (float*)(w + alloc((size_t)N*4));
    float* bufA  = (float*)(w + alloc((size_t)N*HF*4));
    float* bufB  = (float*)(w + alloc((size_t)N*HF*4));

    hipMemsetAsync(d_ws, 0, zero_bytes, stream);

    const int* src = ei;
    const int* dst = ei + E;
    int NB1 = (N + 255) / 256;
    int NC  = (E + 8191) / 8192;
    int GB  = (N + 31) / 32;

    k_mlp    <<<NB1, 256, 0, stream>>>(x, w_in1, b_in1, w_in2, b_in2, bufA, N);
    k_stats  <<<NB1, 256, 0, stream>>>(bufA, stats, N);
    k_binA   <<<NC,  256, 0, stream>>>(dst, gcnt, E, B);
    k_scanB  <<<1,   512, 0, stream>>>(gcnt, boff, B);
    k_binC   <<<NC,  256, 0, stream>>>(src, dst, boff, gfill, ep, E, B);
    k_bucketD<<<B,   256, 0, stream>>>(ep, boff, rowp, dis, esrc, N, E, B);

    k_bn_t1   <<<GB, 256, 0, stream>>>(bufA, stats, gamma, beta, wg1, dis, bufB, N);
    k_gather_t<<<GB, 256, 0, stream>>>((const float4*)bufB, esrc, rowp, dis, bg1, wg2, (float4*)bufA, N);
    k_gather_t<<<GB, 256, 0, stream>>>((const float4*)bufA, esrc, rowp, dis, bg2, wg3, (float4*)bufB, N);
    k_gather_out<<<GB, 256, 0, stream>>>((const float4*)bufB, esrc, rowp, dis, bg3,
                                         wo1, bo1, wo2, bo2, wo3, bo3, (float*)d_out, N);
}

// Round 3
// 341.794 us; speedup vs baseline: 1.7298x; 1.0839x over previous
//
#include <hip/hip_runtime.h>
#include <hip/hip_fp16.h>

#define HF 32
#define EPS 1e-5f
#define BSH 8
#define BSZ 256          // nodes per bucket
#define CH  4096         // edges per binning block

__device__ __forceinline__ float leaky(float v){ return fmaxf(v, 0.01f*v); }
__device__ __forceinline__ float elu1(float v){ return v > 0.f ? v : (expf(v)-1.f); }
__device__ __forceinline__ float sigmoidf(float v){ return 1.f/(1.f+expf(-v)); }

// add a 16-byte row slice (8 halfs) into fp32 accumulator
__device__ __forceinline__ void addrow(float* acc, float4 v){
    const __half2* p = (const __half2*)&v;
#pragma unroll
    for (int k = 0; k < 4; k++){
        float2 f = __half22float2(p[k]);
        acc[2*k]   += f.x;
        acc[2*k+1] += f.y;
    }
}

// ---------------- input MLP: h = leaky(leaky(x@W1+b1)@W2+b2) ----------------
__global__ __launch_bounds__(256)
void k_mlp(const float* __restrict__ x,
           const float* __restrict__ w1, const float* __restrict__ b1,
           const float* __restrict__ w2, const float* __restrict__ b2,
           float* __restrict__ h, int N){
    __shared__ float sW1[3*HF], sB1[HF], sW2[HF*HF], sB2[HF];
    int t = threadIdx.x;
    for (int i = t; i < 3*HF; i += 256) sW1[i] = w1[i];
    if (t < HF){ sB1[t] = b1[t]; sB2[t] = b2[t]; }
    for (int i = t; i < HF*HF; i += 256) sW2[i] = w2[i];
    __syncthreads();
    int n = blockIdx.x*256 + t;
    if (n >= N) return;
    float x0 = x[(size_t)n*3], x1 = x[(size_t)n*3+1], x2 = x[(size_t)n*3+2];
    float h1[HF];
#pragma unroll
    for (int j = 0; j < HF; j++){
        float v = fmaf(x0, sW1[j], fmaf(x1, sW1[HF+j], fmaf(x2, sW1[2*HF+j], sB1[j])));
        h1[j] = leaky(v);
    }
    float4* hv = (float4*)(h + (size_t)n*HF);
#pragma unroll
    for (int jb = 0; jb < 8; jb++){
        float o[4];
#pragma unroll
        for (int c = 0; c < 4; c++){
            int j = jb*4 + c;
            float v = sB2[j];
#pragma unroll
            for (int i = 0; i < HF; i++) v = fmaf(h1[i], sW2[i*HF+j], v);
            o[c] = leaky(v);
        }
        hv[jb] = make_float4(o[0], o[1], o[2], o[3]);
    }
}

// ---------------- batchnorm stats: stats[0..31]=sum, [32..63]=sumsq ----------
__global__ __launch_bounds__(256)
void k_stats(const float* __restrict__ h, float* __restrict__ stats, int N){
    int f = threadIdx.x & 31, j = threadIdx.x >> 5;
    int base = blockIdx.x * 256;
    float s = 0.f, ss = 0.f;
    for (int i = 0; i < 32; i++){
        int n = base + j + i*8;
        if (n < N){ float v = h[(size_t)n*HF + f]; s += v; ss += v*v; }
    }
    __shared__ float ls[HF], lss[HF];
    if (threadIdx.x < HF){ ls[threadIdx.x] = 0.f; lss[threadIdx.x] = 0.f; }
    __syncthreads();
    atomicAdd(&ls[f], s); atomicAdd(&lss[f], ss);
    __syncthreads();
    if (threadIdx.x < HF) atomicAdd(&stats[threadIdx.x], ls[threadIdx.x]);
    else if (threadIdx.x < 2*HF) atomicAdd(&stats[threadIdx.x], lss[threadIdx.x - HF]);
}

// ------------- binning pass A: per-bucket edge counts (LDS-staged) ----------
__global__ __launch_bounds__(256)
void k_binA(const int* __restrict__ dst, int* __restrict__ gcnt, int E, int B){
    __shared__ int l[512];
    int t = threadIdx.x;
    for (int i = t; i < B; i += 256) l[i] = 0;
    __syncthreads();
    int base = blockIdx.x * CH;
    for (int i = 0; i < CH/256; i++){
        int e = base + t + i*256;
        if (e < E) atomicAdd(&l[dst[e] >> BSH], 1);
    }
    __syncthreads();
    for (int i = t; i < B; i += 256){ int c = l[i]; if (c) atomicAdd(&gcnt[i], c); }
}

// ------------- scan bucket counts -> bucket offsets (B <= 512) --------------
__global__ __launch_bounds__(512)
void k_scanB(const int* __restrict__ gcnt, int* __restrict__ boff, int NB){
    __shared__ int l[512];
    int t = threadIdx.x;
    int v = (t < NB) ? gcnt[t] : 0;
    l[t] = v; __syncthreads();
    for (int off = 1; off < 512; off <<= 1){
        int u = (t >= off) ? l[t - off] : 0;
        __syncthreads();
        l[t] += u;
        __syncthreads();
    }
    if (t < NB) boff[t] = l[t] - v;
    if (t == NB-1) boff[NB] = l[t];
}

// ------------- binning pass C: scatter packed edges into bucket segments ----
__global__ __launch_bounds__(256)
void k_binC(const int* __restrict__ src, const int* __restrict__ dst,
            const int* __restrict__ boff, int* __restrict__ gfill,
            int* __restrict__ ep, int E, int B){
    __shared__ int lcnt[512], lbase[512], lpos[512];
    int t = threadIdx.x;
    for (int i = t; i < B; i += 256){ lcnt[i] = 0; lpos[i] = 0; }
    __syncthreads();
    int base = blockIdx.x * CH;
    for (int i = 0; i < CH/256; i++){
        int e = base + t + i*256;
        if (e < E) atomicAdd(&lcnt[dst[e] >> BSH], 1);
    }
    __syncthreads();
    for (int i = t; i < B; i += 256){
        int c = lcnt[i];
        lbase[i] = c ? (boff[i] + atomicAdd(&gfill[i], c)) : 0;
    }
    __syncthreads();
    for (int i = 0; i < CH/256; i++){
        int e = base + t + i*256;
        if (e < E){
            int d = dst[e], b = d >> BSH;
            int p = lbase[b] + atomicAdd(&lpos[b], 1);
            ep[p] = (src[e] << BSH) | (d & (BSZ-1));
        }
    }
}

// ------------- per-bucket CSR build: rowp, dis, esrc ------------------------
__global__ __launch_bounds__(256)
void k_bucketD(const int* __restrict__ ep, const int* __restrict__ boff,
               int* __restrict__ rowp, float* __restrict__ dis,
               int* __restrict__ esrc, int N, int E, int B){
    __shared__ int lcnt[256], lpre[256], lfill[256], sc[256];
    int b = blockIdx.x, t = threadIdx.x;
    int e0 = boff[b], e1 = boff[b+1];
    lcnt[t] = 0; lfill[t] = 0;
    __syncthreads();
    for (int e = e0 + t; e < e1; e += 256) atomicAdd(&lcnt[ep[e] & (BSZ-1)], 1);
    __syncthreads();
    int v = lcnt[t];
    sc[t] = v; __syncthreads();
    for (int off = 1; off < 256; off <<= 1){
        int u = (t >= off) ? sc[t - off] : 0;
        __syncthreads();
        sc[t] += u;
        __syncthreads();
    }
    int pre = sc[t] - v;
    lpre[t] = pre;
    int n = b*BSZ + t;
    if (n < N){
        rowp[n] = e0 + pre;
        dis[n]  = rsqrtf((float)(v + 1));
    }
    if (n == N) rowp[N] = E;
    if (b == B-1 && t == 0 && (N & (BSZ-1)) == 0) rowp[N] = E;
    __syncthreads();
    for (int e = e0 + t; e < e1; e += 256){
        int val = ep[e];
        int d = val & (BSZ-1);
        int p = lpre[d] + atomicAdd(&lfill[d], 1);
        esrc[e0 + p] = val >> BSH;
    }
}

// ------- BN + first transform: t1 = ((bn(h))@W)*dis, fp16 out ---------------
// 64 nodes/block, 4 lanes/node, 8 features/lane
__global__ __launch_bounds__(256)
void k_bn_t1(const float* __restrict__ h, const float* __restrict__ stats,
             const float* __restrict__ gamma, const float* __restrict__ beta,
             const float* __restrict__ W, const float* __restrict__ dis,
             __half* __restrict__ tout, int N){
    __shared__ float sW[HF*HF];
    __shared__ float sh[64][33];
    int tid = threadIdx.x;
    for (int i = tid; i < HF*HF; i += 256) sW[i] = W[i];
    int nib = tid >> 2, l = tid & 3;
    int n = blockIdx.x*64 + nib;
    float hv[8];
    float d = 0.f;
    if (n < N){
        float4 a = ((const float4*)h)[(size_t)n*8 + 2*l];
        float4 b = ((const float4*)h)[(size_t)n*8 + 2*l + 1];
        float tmp[8] = {a.x,a.y,a.z,a.w,b.x,b.y,b.z,b.w};
        d = dis[n];
        float inv = 1.0f / (float)N;
#pragma unroll
        for (int c = 0; c < 8; c++){
            int f = 8*l + c;
            float mu  = stats[f]    * inv;
            float var = stats[HF+f] * inv - mu*mu;
            float rs  = rsqrtf(var + EPS);
            hv[c] = (tmp[c] - mu) * rs * gamma[f] + beta[f];
        }
    } else {
#pragma unroll
        for (int c = 0; c < 8; c++) hv[c] = 0.f;
    }
    __syncthreads();                // covers sW writes
#pragma unroll
    for (int c = 0; c < 8; c++) sh[nib][8*l + c] = hv[c];
    __syncthreads();
    float o[8] = {0.f,0.f,0.f,0.f,0.f,0.f,0.f,0.f};
#pragma unroll
    for (int i = 0; i < HF; i++){
        float hvv = sh[nib][i];
        float4 w0 = *(const float4*)&sW[i*HF + 8*l];
        float4 w1 = *(const float4*)&sW[i*HF + 8*l + 4];
        o[0] = fmaf(hvv, w0.x, o[0]); o[1] = fmaf(hvv, w0.y, o[1]);
        o[2] = fmaf(hvv, w0.z, o[2]); o[3] = fmaf(hvv, w0.w, o[3]);
        o[4] = fmaf(hvv, w1.x, o[4]); o[5] = fmaf(hvv, w1.y, o[5]);
        o[6] = fmaf(hvv, w1.z, o[6]); o[7] = fmaf(hvv, w1.w, o[7]);
    }
    if (n < N){
        __half2 hh[4];
#pragma unroll
        for (int k = 0; k < 4; k++)
            hh[k] = __float22half2_rn(make_float2(o[2*k]*d, o[2*k+1]*d));
        ((float4*)tout)[(size_t)n*4 + l] = *(float4*)hh;
    }
}

// ------- fused gather + next transform (fp16 in/out) ------------------------
__global__ __launch_bounds__(256)
void k_gather_t(const __half* __restrict__ tin, const int* __restrict__ esrc,
                const int* __restrict__ rowp, const float* __restrict__ dis,
                const float* __restrict__ bias, const float* __restrict__ W,
                __half* __restrict__ tout, int N){
    __shared__ float sW[HF*HF];
    __shared__ float sh[64][33];
    int tid = threadIdx.x;
    for (int i = tid; i < HF*HF; i += 256) sW[i] = W[i];
    int nib = tid >> 2, l = tid & 3;
    int n = blockIdx.x*64 + nib;
    float acc[8] = {0.f,0.f,0.f,0.f,0.f,0.f,0.f,0.f};
    float d = 0.f;
    const float4* tv = (const float4*)tin;
    if (n < N){
        addrow(acc, tv[(size_t)n*4 + l]);    // self loop
        int e0 = rowp[n], e1 = rowp[n+1];
        int e = e0;
        for (; e + 3 < e1; e += 4){
            int s0 = esrc[e], s1 = esrc[e+1], s2 = esrc[e+2], s3 = esrc[e+3];
            float4 v0 = tv[(size_t)s0*4 + l];
            float4 v1 = tv[(size_t)s1*4 + l];
            float4 v2 = tv[(size_t)s2*4 + l];
            float4 v3 = tv[(size_t)s3*4 + l];
            addrow(acc, v0); addrow(acc, v1); addrow(acc, v2); addrow(acc, v3);
        }
        for (; e < e1; e++){
            addrow(acc, tv[(size_t)esrc[e]*4 + l]);
        }
        d = dis[n];
#pragma unroll
        for (int c = 0; c < 8; c++)
            acc[c] = elu1(fmaf(d, acc[c], bias[8*l + c]));
    }
    __syncthreads();                // covers sW writes
#pragma unroll
    for (int c = 0; c < 8; c++) sh[nib][8*l + c] = acc[c];
    __syncthreads();
    float o[8] = {0.f,0.f,0.f,0.f,0.f,0.f,0.f,0.f};
#pragma unroll
    for (int i = 0; i < HF; i++){
        float hvv = sh[nib][i];
        float4 w0 = *(const float4*)&sW[i*HF + 8*l];
        float4 w1 = *(const float4*)&sW[i*HF + 8*l + 4];
        o[0] = fmaf(hvv, w0.x, o[0]); o[1] = fmaf(hvv, w0.y, o[1]);
        o[2] = fmaf(hvv, w0.z, o[2]); o[3] = fmaf(hvv, w0.w, o[3]);
        o[4] = fmaf(hvv, w1.x, o[4]); o[5] = fmaf(hvv, w1.y, o[5]);
        o[6] = fmaf(hvv, w1.z, o[6]); o[7] = fmaf(hvv, w1.w, o[7]);
    }
    if (n < N){
        __half2 hh[4];
#pragma unroll
        for (int k = 0; k < 4; k++)
            hh[k] = __float22half2_rn(make_float2(o[2*k]*d, o[2*k+1]*d));
        ((float4*)tout)[(size_t)n*4 + l] = *(float4*)hh;
    }
}

// ------- final: gather layer3 + elu, output MLP + sigmoid on col 0 ----------
__global__ __launch_bounds__(256)
void k_gather_out(const __half* __restrict__ tin, const int* __restrict__ esrc,
                  const int* __restrict__ rowp, const float* __restrict__ dis,
                  const float* __restrict__ bg3,
                  const float* __restrict__ wo1, const float* __restrict__ bo1,
                  const float* __restrict__ wo2, const float* __restrict__ bo2,
                  const float* __restrict__ wo3, const float* __restrict__ bo3,
                  float* __restrict__ out, int N){
    __shared__ float sW1[HF*HF], sW2[HF*HF], sW3[HF*4];
    __shared__ float sh[64][33], sh2[64][33];
    int tid = threadIdx.x;
    for (int i = tid; i < HF*HF; i += 256){ sW1[i] = wo1[i]; sW2[i] = wo2[i]; }
    if (tid < HF*4) sW3[tid] = wo3[tid];
    int nib = tid >> 2, l = tid & 3;
    int n = blockIdx.x*64 + nib;
    float acc[8] = {0.f,0.f,0.f,0.f,0.f,0.f,0.f,0.f};
    const float4* tv = (const float4*)tin;
    if (n < N){
        addrow(acc, tv[(size_t)n*4 + l]);
        int e0 = rowp[n], e1 = rowp[n+1];
        int e = e0;
        for (; e + 3 < e1; e += 4){
            int s0 = esrc[e], s1 = esrc[e+1], s2 = esrc[e+2], s3 = esrc[e+3];
            float4 v0 = tv[(size_t)s0*4 + l];
            float4 v1 = tv[(size_t)s1*4 + l];
            float4 v2 = tv[(size_t)s2*4 + l];
            float4 v3 = tv[(size_t)s3*4 + l];
            addrow(acc, v0); addrow(acc, v1); addrow(acc, v2); addrow(acc, v3);
        }
        for (; e < e1; e++){
            addrow(acc, tv[(size_t)esrc[e]*4 + l]);
        }
        float d = dis[n];
#pragma unroll
        for (int c = 0; c < 8; c++)
            acc[c] = elu1(fmaf(d, acc[c], bg3[8*l + c]));
    }
    __syncthreads();                // covers weight loads
#pragma unroll
    for (int c = 0; c < 8; c++) sh[nib][8*l + c] = acc[c];
    __syncthreads();
    // r1 = leaky(h@wo1 + bo1)
    float o1[8];
#pragma unroll
    for (int c = 0; c < 8; c++) o1[c] = bo1[8*l + c];
#pragma unroll
    for (int i = 0; i < HF; i++){
        float hvv = sh[nib][i];
        float4 w0 = *(const float4*)&sW1[i*HF + 8*l];
        float4 w1 = *(const float4*)&sW1[i*HF + 8*l + 4];
        o1[0] = fmaf(hvv, w0.x, o1[0]); o1[1] = fmaf(hvv, w0.y, o1[1]);
        o1[2] = fmaf(hvv, w0.z, o1[2]); o1[3] = fmaf(hvv, w0.w, o1[3]);
        o1[4] = fmaf(hvv, w1.x, o1[4]); o1[5] = fmaf(hvv, w1.y, o1[5]);
        o1[6] = fmaf(hvv, w1.z, o1[6]); o1[7] = fmaf(hvv, w1.w, o1[7]);
    }
#pragma unroll
    for (int c = 0; c < 8; c++) sh2[nib][8*l + c] = leaky(o1[c]);
    __syncthreads();
    // r2 = leaky(r1@wo2 + bo2)
    float o2[8];
#pragma unroll
    for (int c = 0; c < 8; c++) o2[c] = bo2[8*l + c];
#pragma unroll
    for (int i = 0; i < HF; i++){
        float hvv = sh2[nib][i];
        float4 w0 = *(const float4*)&sW2[i*HF + 8*l];
        float4 w1 = *(const float4*)&sW2[i*HF + 8*l + 4];
        o2[0] = fmaf(hvv, w0.x, o2[0]); o2[1] = fmaf(hvv, w0.y, o2[1]);
        o2[2] = fmaf(hvv, w0.z, o2[2]); o2[3] = fmaf(hvv, w0.w, o2[3]);
        o2[4] = fmaf(hvv, w1.x, o2[4]); o2[5] = fmaf(hvv, w1.y, o2[5]);
        o2[6] = fmaf(hvv, w1.z, o2[6]); o2[7] = fmaf(hvv, w1.w, o2[7]);
    }
#pragma unroll
    for (int c = 0; c < 8; c++) sh[nib][8*l + c] = leaky(o2[c]);
    __syncthreads();
    // out = r2@wo3 + bo3 ; sigmoid col 0
    if (n < N){
        float v = bo3[l];
#pragma unroll
        for (int i = 0; i < HF; i++) v = fmaf(sh[nib][i], sW3[i*4 + l], v);
        if (l == 0) v = sigmoidf(v);
        out[(size_t)n*4 + l] = v;
    }
}

extern "C" void kernel_launch(void* const* d_in, const int* in_sizes, int n_in,
                              void* d_out, int out_size, void* d_ws, size_t ws_size,
                              hipStream_t stream) {
    const float* x     = (const float*)d_in[0];
    const float* w_in1 = (const float*)d_in[1];
    const float* b_in1 = (const float*)d_in[2];
    const float* w_in2 = (const float*)d_in[3];
    const float* b_in2 = (const float*)d_in[4];
    const float* gamma = (const float*)d_in[5];
    const float* beta  = (const float*)d_in[6];
    const float* wg1   = (const float*)d_in[7];
    const float* bg1   = (const float*)d_in[8];
    const float* wg2   = (const float*)d_in[9];
    const float* bg2   = (const float*)d_in[10];
    const float* wg3   = (const float*)d_in[11];
    const float* bg3   = (const float*)d_in[12];
    const float* wo1   = (const float*)d_in[13];
    const float* bo1   = (const float*)d_in[14];
    const float* wo2   = (const float*)d_in[15];
    const float* bo2   = (const float*)d_in[16];
    const float* wo3   = (const float*)d_in[17];
    const float* bo3   = (const float*)d_in[18];
    const int*   ei    = (const int*)d_in[19];

    int N = in_sizes[0] / 3;
    int E = in_sizes[19] / 2;
    int B = (N + BSZ - 1) >> BSH;          // buckets (<=512 required)

    char* w = (char*)d_ws;
    size_t o = 0;
    auto alloc = [&](size_t bytes){ size_t r = o; o = (o + bytes + 255) & ~(size_t)255; return r; };
    // ---- zeroed region ----
    float* stats = (float*)(w + alloc(2*HF*sizeof(float)));
    int*   gcnt  = (int*)  (w + alloc((size_t)B*4));
    int*   gfill = (int*)  (w + alloc((size_t)B*4));
    size_t zero_bytes = o;
    // ---- rest ----
    int*   boff  = (int*)  (w + alloc(((size_t)B+1)*4));
    int*   ep    = (int*)  (w + alloc((size_t)E*4));
    int*   esrc  = (int*)  (w + alloc((size_t)E*4));
    int*   rowp  = (int*)  (w + alloc(((size_t)N+1)*4));
    float* dis   = (float*)(w + alloc((size_t)N*4));
    float* bufH  = (float*)(w + alloc((size_t)N*HF*4));   // fp32 MLP output
    __half* tA   = (__half*)(w + alloc((size_t)N*HF*2));  // fp16 t buffers
    __half* tB   = (__half*)(w + alloc((size_t)N*HF*2));

    hipMemsetAsync(d_ws, 0, zero_bytes, stream);

    const int* src = ei;
    const int* dst = ei + E;
    int NB1 = (N + 255) / 256;
    int NC  = (E + CH - 1) / CH;
    int GB  = (N + 63) / 64;

    k_mlp    <<<NB1, 256, 0, stream>>>(x, w_in1, b_in1, w_in2, b_in2, bufH, N);
    k_stats  <<<NB1, 256, 0, stream>>>(bufH, stats, N);
    k_binA   <<<NC,  256, 0, stream>>>(dst, gcnt, E, B);
    k_scanB  <<<1,   512, 0, stream>>>(gcnt, boff, B);
    k_binC   <<<NC,  256, 0, stream>>>(src, dst, boff, gfill, ep, E, B);
    k_bucketD<<<B,   256, 0, stream>>>(ep, boff, rowp, dis, esrc, N, E, B);

    k_bn_t1   <<<GB, 256, 0, stream>>>(bufH, stats, gamma, beta, wg1, dis, tA, N);
    k_gather_t<<<GB, 256, 0, stream>>>(tA, esrc, rowp, dis, bg1, wg2, tB, N);
    k_gather_t<<<GB, 256, 0, stream>>>(tB, esrc, rowp, dis, bg2, wg3, tA, N);
    k_gather_out<<<GB, 256, 0, stream>>>(tA, esrc, rowp, dis, bg3,
                                         wo1, bo1, wo2, bo2, wo3, bo3, (float*)d_out, N);
}